// Round 10
// baseline (108.931 us; speedup 1.0000x reference)
//
#include <hip/hip_runtime.h>
#include <hip/hip_bf16.h>
#include <math.h>

#define N_PTS  131072
#define K_DIM  16
#define D_BINS 1024
// packed-screen commit margin: quantize (2^-11=4.88e-4) + screen err (~5e-5)
#define MARGIN_P 6e-4f

typedef short bf16x8 __attribute__((ext_vector_type(8)));
typedef float f32x4  __attribute__((ext_vector_type(4)));

// ws layout (bytes):
// [0,4) wl_count | [64,+64K) bnT rows | [65600,+32K) B1 | [98368,+32K) B2
// | [131136,+16) zero | [131152,+512K) wl   total 655,440 <= proven floor
#define WS_OFF_BN  64
#define WS_OFF_B1  65600
#define WS_OFF_B2  98368
#define WS_OFF_Z   131136
#define WS_OFF_WL  131152
#define WS_NEED    655440

// np-exact normalization over K (sequential ascending k, no fma).
__device__ __forceinline__ void norm_np(const float* __restrict__ p,
                                        int stride, int n, float* __restrict__ a) {
#pragma clang fp contract(off)
    float v[K_DIM];
#pragma unroll
    for (int k = 0; k < K_DIM; ++k) v[k] = p[(size_t)k * stride + n];
    float s = v[0];
#pragma unroll
    for (int k = 1; k < K_DIM; ++k) s = s + v[k];
    const float mean = s / 16.0f;
    float sq[K_DIM];
#pragma unroll
    for (int k = 0; k < K_DIM; ++k) { a[k] = v[k] - mean; sq[k] = a[k] * a[k]; }
    float ss = sq[0];
#pragma unroll
    for (int k = 1; k < K_DIM; ++k) ss = ss + sq[k];
    const float denom = sqrtf(ss) + 1e-10f;
#pragma unroll
    for (int k = 0; k < K_DIM; ++k) a[k] = a[k] / denom;
}

__device__ __forceinline__ unsigned short bf16_bits(float f) {
    __hip_bfloat16 h = __float2bfloat16(f);   // RNE
    unsigned short u;
    __builtin_memcpy(&u, &h, 2);
    return u;
}
__device__ __forceinline__ float bf16_val(float f) {
    return __bfloat162float(__float2bfloat16(f));
}

// Kernel 1: np-exact cmat normalize -> bnT rows + hi/lo MFMA B-fragments
// (layout verified R8/R9); zero wl counter + global zero block.
__global__ __launch_bounds__(256) void prep_b(
    const float* __restrict__ cmat, float* __restrict__ bnT,
    unsigned short* __restrict__ B1, unsigned short* __restrict__ B2,
    unsigned short* __restrict__ zblk, int* __restrict__ wl_count) {
#pragma clang fp contract(off)
    if (blockIdx.x == 0) {
        if (threadIdx.x == 0) *wl_count = 0;
        if (threadIdx.x < 8) zblk[threadIdx.x] = 0;
    }
    const int d = blockIdx.x * 256 + threadIdx.x;   // grid = 4 * 256
    if (d >= D_BINS) return;

    float t[K_DIM];
    norm_np(cmat, D_BINS, d, t);

    const int tile = d >> 4, n = d & 15;
#pragma unroll
    for (int k = 0; k < K_DIM; ++k) {
        bnT[d * K_DIM + k] = t[k];
        const float hi_f = bf16_val(t[k]);
        const int idx = tile * 256 + ((k >> 3) * 16 + n) * 8 + (k & 7);
        B1[idx] = bf16_bits(t[k]);
        B2[idx] = bf16_bits(t[k] - hi_f);
    }
}

// Kernel 2: MFMA screen, occupancy-first. Block = 512 thr (8 waves), LDS
// holds ONLY B1 (32 KB) -> 4 blocks/CU = 32 waves/CU. B2 (lo) read from
// global (L1-resident 32 KB; lanes>=32 -> zero block). Wave owns 16 points;
// per bin-tile: acc = mfma(A,b_hi,C=2.0); acc = mfma(A,b_lo,acc).
// Top-2 tracked as packed uint (score&~0x7FF)|(2047-d): uint max == higher
// score, ties -> lower d (np first-max-wins).
__global__ __launch_bounds__(512, 8) void mfma_screen(
    const float* __restrict__ x, const unsigned short* __restrict__ B1,
    const unsigned short* __restrict__ B2, const unsigned short* __restrict__ zblk,
    int* __restrict__ out, int* __restrict__ wl, int* __restrict__ wl_count) {
#pragma clang fp contract(off)
    __shared__ float4 ldsB[2048];     // B1: 32 KB

    {
        const float4* src = (const float4*)B1;
#pragma unroll
        for (int j = 0; j < 4; ++j)
            ldsB[threadIdx.x + j * 512] = src[threadIdx.x + j * 512];
    }

    const int lane = threadIdx.x & 63;
    const int wv   = threadIdx.x >> 6;              // 0..7
    const int W    = blockIdx.x * 8 + wv;           // grid = 1024 * 512
    const int P    = W * 16;
    const int m    = lane & 15;                     // bin column within tile
    const int q    = lane >> 4;                     // quad

    // A fragment (16 points): kp=(lane>>4)*8+j; kp<16 -> hi, kp>=16 -> lo.
    bf16x8 A;
    {
        float a[K_DIM];
        norm_np(x, N_PTS, P + m, a);
        unsigned short els[8];
#pragma unroll
        for (int j = 0; j < 8; ++j) {
            const int k = (q & 1) * 8 + j;
            if (q < 2) els[j] = bf16_bits(a[k]);
            else       els[j] = bf16_bits(a[k] - bf16_val(a[k]));
        }
        __builtin_memcpy(&A, els, 16);
    }

    __syncthreads();

    const char* b1p = (const char*)ldsB + (size_t)(lane & 31) * 16;
    const char* b2p = (lane < 32) ? ((const char*)B2 + (size_t)lane * 16)
                                  : (const char*)zblk;
    const int   b2s = (lane < 32) ? 512 : 0;

    unsigned ub1[4], ub2[4];
#pragma unroll
    for (int r = 0; r < 4; ++r) { ub1[r] = 0u; ub2[r] = 0u; }

    const unsigned mask = 0xFFFFF800u;

    for (int i = 0; i < 64; ++i) {
        bf16x8 bf1, bf2;
        __builtin_memcpy(&bf1, b1p + (size_t)i * 512, 16);
        __builtin_memcpy(&bf2, b2p + (size_t)i * b2s, 16);

        f32x4 acc = __builtin_amdgcn_mfma_f32_16x16x32_bf16(
            A, bf1, (f32x4){2.f, 2.f, 2.f, 2.f}, 0, 0, 0);
        acc = __builtin_amdgcn_mfma_f32_16x16x32_bf16(A, bf2, acc, 0, 0, 0);

        const unsigned dcomp = 2047u - (unsigned)(i * 16 + m);
#pragma unroll
        for (int r = 0; r < 4; ++r) {
            const unsigned u = (__float_as_uint(acc[r]) & mask) | dcomp;
            const unsigned nx = max(ub1[r], u);
            ub2[r] = max(ub2[r], min(ub1[r], u));
            ub1[r] = nx;
        }
    }

    // merge top-2 across the 16 bin-columns (m) of each quad group
#pragma unroll
    for (int r = 0; r < 4; ++r) {
        unsigned u1 = ub1[r], u2 = ub2[r];
#pragma unroll
        for (int s = 1; s <= 8; s <<= 1) {
            const unsigned o1 = (unsigned)__shfl_xor((int)u1, s, 16);
            const unsigned o2 = (unsigned)__shfl_xor((int)u2, s, 16);
            const unsigned n1 = max(u1, o1);
            u2 = max(min(u1, o1), max(u2, o2));
            u1 = n1;
        }
        if (m == 0) {
            const int p  = P + q * 4 + r;
            const float s1 = __uint_as_float(u1 & mask);
            const float s2 = __uint_as_float(u2 & mask);
            if (s1 - s2 > MARGIN_P) {
                out[p] = 2047 - (int)(u1 & 2047u);
            } else {
                const int pos = atomicAdd(wl_count, 1);
                wl[pos] = p;
            }
        }
    }
}

// Kernel 3: np-exact rescan, one wave per worklisted point (proven R7-R9).
__global__ __launch_bounds__(256) void ncc_exact_refine(
    const float* __restrict__ x, const float* __restrict__ bnT,
    int* __restrict__ out, const int* __restrict__ wl,
    const int* __restrict__ wl_count) {
#pragma clang fp contract(off)
    const int count  = *wl_count;
    const int lane   = threadIdx.x & 63;
    const int wave   = (blockIdx.x * 256 + threadIdx.x) >> 6;
    const int nwaves = (gridDim.x * 256) >> 6;

    for (int i = wave; i < count; i += nwaves) {
        const int n = wl[i];
        float a[K_DIM];
        norm_np(x, N_PTS, n, a);

        float best = -3.402823466e38f;
        int   idx  = 0x7fffffff;
        const float4* b4 = (const float4*)bnT;
        for (int t = 0; t < 16; ++t) {
            const int d = t * 64 + lane;
            const float4 q0 = b4[d * 4 + 0];
            const float4 q1 = b4[d * 4 + 1];
            const float4 q2 = b4[d * 4 + 2];
            const float4 q3 = b4[d * 4 + 3];
            float sc;
            sc = a[0] * q0.x;
            sc = sc + a[1]  * q0.y; sc = sc + a[2]  * q0.z; sc = sc + a[3]  * q0.w;
            sc = sc + a[4]  * q1.x; sc = sc + a[5]  * q1.y; sc = sc + a[6]  * q1.z;
            sc = sc + a[7]  * q1.w; sc = sc + a[8]  * q2.x; sc = sc + a[9]  * q2.y;
            sc = sc + a[10] * q2.z; sc = sc + a[11] * q2.w; sc = sc + a[12] * q3.x;
            sc = sc + a[13] * q3.y; sc = sc + a[14] * q3.z; sc = sc + a[15] * q3.w;
            if (sc > best) { best = sc; idx = d; }
        }
#pragma unroll
        for (int mk = 1; mk <= 32; mk <<= 1) {
            const float ob = __shfl_xor(best, mk);
            const int   oi = __shfl_xor(idx,  mk);
            if (ob > best || (ob == best && oi < idx)) { best = ob; idx = oi; }
        }
        if (lane == 0) out[n] = idx;
    }
}

// Fallback (small ws): proven-exact full scan (R4).
__global__ __launch_bounds__(256) void ncc_argmax_np32(
    const float* __restrict__ x, const float* __restrict__ bnT,
    int* __restrict__ out) {
#pragma clang fp contract(off)
    const int n = blockIdx.x * 256 + threadIdx.x;
    float a[K_DIM];
    norm_np(x, N_PTS, n, a);

    float best = -3.402823466e38f;
    int   idx  = 0;
    const float4* b4 = (const float4*)bnT;
#pragma unroll 2
    for (int d = 0; d < D_BINS; ++d) {
        const float4 q0 = b4[d * 4 + 0];
        const float4 q1 = b4[d * 4 + 1];
        const float4 q2 = b4[d * 4 + 2];
        const float4 q3 = b4[d * 4 + 3];
        float sc;
        sc = a[0] * q0.x;
        sc = sc + a[1]  * q0.y; sc = sc + a[2]  * q0.z; sc = sc + a[3]  * q0.w;
        sc = sc + a[4]  * q1.x; sc = sc + a[5]  * q1.y; sc = sc + a[6]  * q1.z;
        sc = sc + a[7]  * q1.w; sc = sc + a[8]  * q2.x; sc = sc + a[9]  * q2.y;
        sc = sc + a[10] * q2.z; sc = sc + a[11] * q2.w; sc = sc + a[12] * q3.x;
        sc = sc + a[13] * q3.y; sc = sc + a[14] * q3.z; sc = sc + a[15] * q3.w;
        if (sc > best) { best = sc; idx = d; }
    }
    out[n] = idx;
}

__global__ __launch_bounds__(256) void normalize_rows_only(
    const float* __restrict__ cmat, float* __restrict__ bnT) {
#pragma clang fp contract(off)
    const int d = blockIdx.x * 256 + threadIdx.x;
    if (d >= D_BINS) return;
    float t[K_DIM];
    norm_np(cmat, D_BINS, d, t);
#pragma unroll
    for (int k = 0; k < K_DIM; ++k) bnT[d * K_DIM + k] = t[k];
}

extern "C" void kernel_launch(void* const* d_in, const int* in_sizes, int n_in,
                              void* d_out, int out_size, void* d_ws, size_t ws_size,
                              hipStream_t stream) {
    const float* x    = (const float*)d_in[0];   // [1, 16, 131072] fp32
    const float* cmat = (const float*)d_in[1];   // [16, 1024] fp32
    int* out = (int*)d_out;                      // [1, 131072] int32
    char* ws = (char*)d_ws;

    if (ws_size >= (size_t)WS_NEED) {
        int*            wl_count = (int*)ws;
        float*          bnT      = (float*)(ws + WS_OFF_BN);
        unsigned short* B1       = (unsigned short*)(ws + WS_OFF_B1);
        unsigned short* B2       = (unsigned short*)(ws + WS_OFF_B2);
        unsigned short* zblk     = (unsigned short*)(ws + WS_OFF_Z);
        int*            wl       = (int*)(ws + WS_OFF_WL);

        prep_b<<<4, 256, 0, stream>>>(cmat, bnT, B1, B2, zblk, wl_count);
        mfma_screen<<<1024, 512, 0, stream>>>(x, B1, B2, zblk, out, wl, wl_count);
        ncc_exact_refine<<<512, 256, 0, stream>>>(x, bnT, out, wl, wl_count);
    } else {
        float* bnT = (float*)(ws + WS_OFF_BN);
        normalize_rows_only<<<4, 256, 0, stream>>>(cmat, bnT);
        ncc_argmax_np32<<<512, 256, 0, stream>>>(x, bnT, out);
    }
}

// Round 11
// 106.598 us; speedup vs baseline: 1.0219x; 1.0219x over previous
//
#include <hip/hip_runtime.h>
#include <hip/hip_bf16.h>
#include <math.h>

#define N_PTS  131072
#define K_DIM  16
#define D_BINS 1024
// packed-screen commit margin: quantize (2^-11=4.88e-4) + screen err (~5e-5)
#define MARGIN_P 6e-4f

typedef short bf16x8 __attribute__((ext_vector_type(8)));
typedef float f32x4  __attribute__((ext_vector_type(4)));

// ws layout (bytes):
// [0,4) wl_count | [64,+64K) bnT rows | [65600,+32K) B1 | [98368,+32K) B2
// | [131136,+16) zero uint4 (== B2 entry 2048) | [131152,+512K) wl
#define WS_OFF_BN  64
#define WS_OFF_B1  65600
#define WS_OFF_B2  98368
#define WS_OFF_Z   131136
#define WS_OFF_WL  131152
#define WS_NEED    655440

// np-exact normalization over K (sequential ascending k, no fma).
__device__ __forceinline__ void norm_np(const float* __restrict__ p,
                                        int stride, int n, float* __restrict__ a) {
#pragma clang fp contract(off)
    float v[K_DIM];
#pragma unroll
    for (int k = 0; k < K_DIM; ++k) v[k] = p[(size_t)k * stride + n];
    float s = v[0];
#pragma unroll
    for (int k = 1; k < K_DIM; ++k) s = s + v[k];
    const float mean = s / 16.0f;
    float sq[K_DIM];
#pragma unroll
    for (int k = 0; k < K_DIM; ++k) { a[k] = v[k] - mean; sq[k] = a[k] * a[k]; }
    float ss = sq[0];
#pragma unroll
    for (int k = 1; k < K_DIM; ++k) ss = ss + sq[k];
    const float denom = sqrtf(ss) + 1e-10f;
#pragma unroll
    for (int k = 0; k < K_DIM; ++k) a[k] = a[k] / denom;
}

__device__ __forceinline__ unsigned short bf16_bits(float f) {
    __hip_bfloat16 h = __float2bfloat16(f);   // RNE
    unsigned short u;
    __builtin_memcpy(&u, &h, 2);
    return u;
}
__device__ __forceinline__ float bf16_val(float f) {
    return __bfloat162float(__float2bfloat16(f));
}

// Kernel 1: np-exact cmat normalize -> bnT rows + hi/lo MFMA B-fragments
// (layout verified R8-R10); zero wl counter + zero uint4 at B2[2048].
__global__ __launch_bounds__(256) void prep_b(
    const float* __restrict__ cmat, float* __restrict__ bnT,
    unsigned short* __restrict__ B1, unsigned short* __restrict__ B2,
    unsigned short* __restrict__ zblk, int* __restrict__ wl_count) {
#pragma clang fp contract(off)
    if (blockIdx.x == 0) {
        if (threadIdx.x == 0) *wl_count = 0;
        if (threadIdx.x < 8) zblk[threadIdx.x] = 0;
    }
    const int d = blockIdx.x * 256 + threadIdx.x;   // grid = 4 * 256
    if (d >= D_BINS) return;

    float t[K_DIM];
    norm_np(cmat, D_BINS, d, t);

    const int tile = d >> 4, n = d & 15;
#pragma unroll
    for (int k = 0; k < K_DIM; ++k) {
        bnT[d * K_DIM + k] = t[k];
        const float hi_f = bf16_val(t[k]);
        const int idx = tile * 256 + ((k >> 3) * 16 + n) * 8 + (k & 7);
        B1[idx] = bf16_bits(t[k]);
        B2[idx] = bf16_bits(t[k] - hi_f);
    }
}

// Kernel 2: MFMA screen. Typed uint4 loads ONLY in the hot loop
// (ds_read_b128 / global_load_dwordx4 guaranteed; bit_cast to bf16x8).
// Block = 512 thr (8 waves), LDS = B1 only (32 KB) -> 4 blocks/CU.
// Wave owns 16 points; per bin-tile:
//   acc = mfma(A, b_hi, C=2.0); acc = mfma(A, b_lo, acc)
// Top-2 tracked as packed uint (score&~0x7FF)|(2047-d): uint max == higher
// score, ties -> lower d (np first-max-wins).
__global__ __launch_bounds__(512, 8) void mfma_screen(
    const float* __restrict__ x, const uint4* __restrict__ B1,
    const uint4* __restrict__ B2,
    int* __restrict__ out, int* __restrict__ wl, int* __restrict__ wl_count) {
#pragma clang fp contract(off)
    __shared__ uint4 ldsB[2048];     // B1: 32 KB

    {
#pragma unroll
        for (int j = 0; j < 4; ++j)
            ldsB[threadIdx.x + j * 512] = B1[threadIdx.x + j * 512];
    }

    const int lane = threadIdx.x & 63;
    const int wv   = threadIdx.x >> 6;              // 0..7
    const int W    = blockIdx.x * 8 + wv;           // grid = 1024 * 512
    const int P    = W * 16;
    const int m    = lane & 15;                     // bin column within tile
    const int q    = lane >> 4;                     // quad

    // A fragment (16 points): kp=(lane>>4)*8+j; kp<16 -> hi, kp>=16 -> lo.
    bf16x8 A;
    {
        float a[K_DIM];
        norm_np(x, N_PTS, P + m, a);
        unsigned short els[8];
#pragma unroll
        for (int j = 0; j < 8; ++j) {
            const int k = (q & 1) * 8 + j;
            if (q < 2) els[j] = bf16_bits(a[k]);
            else       els[j] = bf16_bits(a[k] - bf16_val(a[k]));
        }
        __builtin_memcpy(&A, els, 16);
    }

    __syncthreads();

    // B1 from LDS (lanes mirrored: L and L+32 same address -> broadcast).
    // B2 from global; lanes>=32 index the zero entry at 2048 (stride 0).
    const uint4* b1p = ldsB + (lane & 31);
    const int b2base = (lane < 32) ? lane : 2048;
    const int b2step = (lane < 32) ? 32 : 0;

    unsigned ub1[4], ub2[4];
#pragma unroll
    for (int r = 0; r < 4; ++r) { ub1[r] = 0u; ub2[r] = 0u; }

    const unsigned mask  = 0xFFFFF800u;
    const unsigned dbase = 2047u - (unsigned)m;

#pragma unroll 4
    for (int i = 0; i < 64; ++i) {
        const uint4 w1 = b1p[i * 32];
        const uint4 w2 = B2[b2base + i * b2step];
        const bf16x8 bf1 = __builtin_bit_cast(bf16x8, w1);
        const bf16x8 bf2 = __builtin_bit_cast(bf16x8, w2);

        f32x4 acc = __builtin_amdgcn_mfma_f32_16x16x32_bf16(
            A, bf1, (f32x4){2.f, 2.f, 2.f, 2.f}, 0, 0, 0);
        acc = __builtin_amdgcn_mfma_f32_16x16x32_bf16(A, bf2, acc, 0, 0, 0);

        const unsigned dcomp = dbase - (unsigned)(i * 16);
#pragma unroll
        for (int r = 0; r < 4; ++r) {
            const unsigned u = (__float_as_uint(acc[r]) & mask) | dcomp;
            const unsigned nx = max(ub1[r], u);
            ub2[r] = max(ub2[r], min(ub1[r], u));
            ub1[r] = nx;
        }
    }

    // merge top-2 across the 16 bin-columns (m) of each quad group
#pragma unroll
    for (int r = 0; r < 4; ++r) {
        unsigned u1 = ub1[r], u2 = ub2[r];
#pragma unroll
        for (int s = 1; s <= 8; s <<= 1) {
            const unsigned o1 = (unsigned)__shfl_xor((int)u1, s, 16);
            const unsigned o2 = (unsigned)__shfl_xor((int)u2, s, 16);
            const unsigned n1 = max(u1, o1);
            u2 = max(min(u1, o1), max(u2, o2));
            u1 = n1;
        }
        if (m == 0) {
            const int p  = P + q * 4 + r;
            const float s1 = __uint_as_float(u1 & mask);
            const float s2 = __uint_as_float(u2 & mask);
            if (s1 - s2 > MARGIN_P) {
                out[p] = 2047 - (int)(u1 & 2047u);
            } else {
                const int pos = atomicAdd(wl_count, 1);
                wl[pos] = p;
            }
        }
    }
}

// Kernel 3: np-exact rescan, one wave per worklisted point (proven R7-R10).
__global__ __launch_bounds__(256) void ncc_exact_refine(
    const float* __restrict__ x, const float* __restrict__ bnT,
    int* __restrict__ out, const int* __restrict__ wl,
    const int* __restrict__ wl_count) {
#pragma clang fp contract(off)
    const int count  = *wl_count;
    const int lane   = threadIdx.x & 63;
    const int wave   = (blockIdx.x * 256 + threadIdx.x) >> 6;
    const int nwaves = (gridDim.x * 256) >> 6;

    for (int i = wave; i < count; i += nwaves) {
        const int n = wl[i];
        float a[K_DIM];
        norm_np(x, N_PTS, n, a);

        float best = -3.402823466e38f;
        int   idx  = 0x7fffffff;
        const float4* b4 = (const float4*)bnT;
        for (int t = 0; t < 16; ++t) {
            const int d = t * 64 + lane;
            const float4 q0 = b4[d * 4 + 0];
            const float4 q1 = b4[d * 4 + 1];
            const float4 q2 = b4[d * 4 + 2];
            const float4 q3 = b4[d * 4 + 3];
            float sc;
            sc = a[0] * q0.x;
            sc = sc + a[1]  * q0.y; sc = sc + a[2]  * q0.z; sc = sc + a[3]  * q0.w;
            sc = sc + a[4]  * q1.x; sc = sc + a[5]  * q1.y; sc = sc + a[6]  * q1.z;
            sc = sc + a[7]  * q1.w; sc = sc + a[8]  * q2.x; sc = sc + a[9]  * q2.y;
            sc = sc + a[10] * q2.z; sc = sc + a[11] * q2.w; sc = sc + a[12] * q3.x;
            sc = sc + a[13] * q3.y; sc = sc + a[14] * q3.z; sc = sc + a[15] * q3.w;
            if (sc > best) { best = sc; idx = d; }
        }
#pragma unroll
        for (int mk = 1; mk <= 32; mk <<= 1) {
            const float ob = __shfl_xor(best, mk);
            const int   oi = __shfl_xor(idx,  mk);
            if (ob > best || (ob == best && oi < idx)) { best = ob; idx = oi; }
        }
        if (lane == 0) out[n] = idx;
    }
}

// Fallback (small ws): proven-exact full scan (R4).
__global__ __launch_bounds__(256) void ncc_argmax_np32(
    const float* __restrict__ x, const float* __restrict__ bnT,
    int* __restrict__ out) {
#pragma clang fp contract(off)
    const int n = blockIdx.x * 256 + threadIdx.x;
    float a[K_DIM];
    norm_np(x, N_PTS, n, a);

    float best = -3.402823466e38f;
    int   idx  = 0;
    const float4* b4 = (const float4*)bnT;
#pragma unroll 2
    for (int d = 0; d < D_BINS; ++d) {
        const float4 q0 = b4[d * 4 + 0];
        const float4 q1 = b4[d * 4 + 1];
        const float4 q2 = b4[d * 4 + 2];
        const float4 q3 = b4[d * 4 + 3];
        float sc;
        sc = a[0] * q0.x;
        sc = sc + a[1]  * q0.y; sc = sc + a[2]  * q0.z; sc = sc + a[3]  * q0.w;
        sc = sc + a[4]  * q1.x; sc = sc + a[5]  * q1.y; sc = sc + a[6]  * q1.z;
        sc = sc + a[7]  * q1.w; sc = sc + a[8]  * q2.x; sc = sc + a[9]  * q2.y;
        sc = sc + a[10] * q2.z; sc = sc + a[11] * q2.w; sc = sc + a[12] * q3.x;
        sc = sc + a[13] * q3.y; sc = sc + a[14] * q3.z; sc = sc + a[15] * q3.w;
        if (sc > best) { best = sc; idx = d; }
    }
    out[n] = idx;
}

__global__ __launch_bounds__(256) void normalize_rows_only(
    const float* __restrict__ cmat, float* __restrict__ bnT) {
#pragma clang fp contract(off)
    const int d = blockIdx.x * 256 + threadIdx.x;
    if (d >= D_BINS) return;
    float t[K_DIM];
    norm_np(cmat, D_BINS, d, t);
#pragma unroll
    for (int k = 0; k < K_DIM; ++k) bnT[d * K_DIM + k] = t[k];
}

extern "C" void kernel_launch(void* const* d_in, const int* in_sizes, int n_in,
                              void* d_out, int out_size, void* d_ws, size_t ws_size,
                              hipStream_t stream) {
    const float* x    = (const float*)d_in[0];   // [1, 16, 131072] fp32
    const float* cmat = (const float*)d_in[1];   // [16, 1024] fp32
    int* out = (int*)d_out;                      // [1, 131072] int32
    char* ws = (char*)d_ws;

    if (ws_size >= (size_t)WS_NEED) {
        int*            wl_count = (int*)ws;
        float*          bnT      = (float*)(ws + WS_OFF_BN);
        unsigned short* B1       = (unsigned short*)(ws + WS_OFF_B1);
        unsigned short* B2       = (unsigned short*)(ws + WS_OFF_B2);
        unsigned short* zblk     = (unsigned short*)(ws + WS_OFF_Z);
        int*            wl       = (int*)(ws + WS_OFF_WL);

        prep_b<<<4, 256, 0, stream>>>(cmat, bnT, B1, B2, zblk, wl_count);
        mfma_screen<<<1024, 512, 0, stream>>>(
            x, (const uint4*)(ws + WS_OFF_B1), (const uint4*)(ws + WS_OFF_B2),
            out, wl, wl_count);
        ncc_exact_refine<<<512, 256, 0, stream>>>(x, bnT, out, wl, wl_count);
    } else {
        float* bnT = (float*)(ws + WS_OFF_BN);
        normalize_rows_only<<<4, 256, 0, stream>>>(cmat, bnT);
        ncc_argmax_np32<<<512, 256, 0, stream>>>(x, bnT, out);
    }
}